// Round 1
// baseline (378.728 us; speedup 1.0000x reference)
//
#include <hip/hip_runtime.h>

// LSTM: B=4096, T=512, INPUT=1, HIDDEN=32, OUTPUT=1 (fp32)
// One batch element per 32-lane half-wave; lane j owns hidden unit j and
// holds the 4 recurrent weight rows for that unit (128 VGPRs). h is
// exchanged per timestep via a broadcast LDS row. x is staged in LDS.

#define HID 32
#define TSTEPS 512
#define BPB 8            // batch elements per block
#define BLOCK 256        // = BPB * 32 threads

__device__ __forceinline__ float fast_sigmoid(float x) {
    return 1.0f / (1.0f + __expf(-x));
}
__device__ __forceinline__ float fast_tanh(float x) {
    // stable: x->+inf => 1, x->-inf => -1 (exp overflow to inf handled)
    return 2.0f / (1.0f + __expf(-2.0f * x)) - 1.0f;
}

__global__ __launch_bounds__(BLOCK, 2)
void lstm_fused_kernel(const float* __restrict__ x,
                       const float* __restrict__ W_ih,
                       const float* __restrict__ W_hh,
                       const float* __restrict__ b_ih,
                       const float* __restrict__ b_hh,
                       const float* __restrict__ W_fc,
                       const float* __restrict__ b_fc,
                       float* __restrict__ out)
{
    __shared__ __align__(16) float x_s[BPB * TSTEPS];   // 16 KiB
    __shared__ __align__(16) float h_s[BPB][HID];       // 1 KiB

    const int tid = threadIdx.x;
    const int lb  = tid >> 5;        // local batch 0..7 (half-wave index)
    const int j   = tid & 31;        // hidden unit
    const int b0  = blockIdx.x * BPB;

    // ---- stage x for this block's 8 contiguous batch rows (coalesced) ----
    {
        const float4* xsrc = reinterpret_cast<const float4*>(x + (size_t)b0 * TSTEPS);
        float4* xdst = reinterpret_cast<float4*>(x_s);
        #pragma unroll
        for (int k = 0; k < (BPB * TSTEPS) / (4 * BLOCK); ++k)
            xdst[tid + k * BLOCK] = xsrc[tid + k * BLOCK];
    }

    // ---- load per-unit weights into registers ----
    float wi[HID], wf[HID], wg[HID], wo[HID];
    {
        const float4* ri = reinterpret_cast<const float4*>(W_hh + (size_t)(0 * HID + j) * HID);
        const float4* rf = reinterpret_cast<const float4*>(W_hh + (size_t)(1 * HID + j) * HID);
        const float4* rg = reinterpret_cast<const float4*>(W_hh + (size_t)(2 * HID + j) * HID);
        const float4* ro = reinterpret_cast<const float4*>(W_hh + (size_t)(3 * HID + j) * HID);
        #pragma unroll
        for (int k = 0; k < HID / 4; ++k) {
            float4 v;
            v = ri[k]; wi[4*k]=v.x; wi[4*k+1]=v.y; wi[4*k+2]=v.z; wi[4*k+3]=v.w;
            v = rf[k]; wf[4*k]=v.x; wf[4*k+1]=v.y; wf[4*k+2]=v.z; wf[4*k+3]=v.w;
            v = rg[k]; wg[4*k]=v.x; wg[4*k+1]=v.y; wg[4*k+2]=v.z; wg[4*k+3]=v.w;
            v = ro[k]; wo[4*k]=v.x; wo[4*k+1]=v.y; wo[4*k+2]=v.z; wo[4*k+3]=v.w;
        }
    }
    const float wih_i = W_ih[j],        wih_f = W_ih[HID + j];
    const float wih_g = W_ih[2*HID + j], wih_o = W_ih[3*HID + j];
    const float bs_i = b_ih[j]         + b_hh[j];
    const float bs_f = b_ih[HID + j]   + b_hh[HID + j];
    const float bs_g = b_ih[2*HID + j] + b_hh[2*HID + j];
    const float bs_o = b_ih[3*HID + j] + b_hh[3*HID + j];

    // ---- init state ----
    h_s[lb][j] = 0.0f;
    float c = 0.0f;
    float hcur = 0.0f;
    __syncthreads();

    // ---- recurrence ----
    #pragma unroll 1
    for (int t = 0; t < TSTEPS; ++t) {
        const float xv = x_s[lb * TSTEPS + t];   // broadcast within half-wave

        // read full h vector for my batch (broadcast LDS reads)
        float hb[HID];
        {
            const float4* hr = reinterpret_cast<const float4*>(&h_s[lb][0]);
            #pragma unroll
            for (int k = 0; k < HID / 4; ++k) {
                float4 v = hr[k];
                hb[4*k]=v.x; hb[4*k+1]=v.y; hb[4*k+2]=v.z; hb[4*k+3]=v.w;
            }
        }

        float ai = fmaf(xv, wih_i, bs_i);
        float af = fmaf(xv, wih_f, bs_f);
        float ag = fmaf(xv, wih_g, bs_g);
        float ao = fmaf(xv, wih_o, bs_o);
        #pragma unroll
        for (int m = 0; m < HID; ++m) {
            ai = fmaf(hb[m], wi[m], ai);
            af = fmaf(hb[m], wf[m], af);
            ag = fmaf(hb[m], wg[m], ag);
            ao = fmaf(hb[m], wo[m], ao);
        }

        const float ig = fast_sigmoid(ai);
        const float fg = fast_sigmoid(af);
        const float gg = fast_tanh(ag);
        const float og = fast_sigmoid(ao);
        c = fmaf(fg, c, ig * gg);
        hcur = og * fast_tanh(c);

        h_s[lb][j] = hcur;
        __syncthreads();   // fence: write(t) visible before reads(t+1)
    }

    // ---- final FC: out[b] = dot(h_T, W_fc) + b_fc ----
    float p = hcur * W_fc[j];
    #pragma unroll
    for (int off = 16; off >= 1; off >>= 1)
        p += __shfl_xor(p, off);   // stays within 32-lane half (masks <= 16)
    if (j == 0)
        out[b0 + lb] = p + b_fc[0];
}

extern "C" void kernel_launch(void* const* d_in, const int* in_sizes, int n_in,
                              void* d_out, int out_size, void* d_ws, size_t ws_size,
                              hipStream_t stream) {
    const float* x    = (const float*)d_in[0];
    const float* W_ih = (const float*)d_in[1];
    const float* W_hh = (const float*)d_in[2];
    const float* b_ih = (const float*)d_in[3];
    const float* b_hh = (const float*)d_in[4];
    const float* W_fc = (const float*)d_in[5];
    const float* b_fc = (const float*)d_in[6];
    float* out = (float*)d_out;

    const int B = in_sizes[0] / TSTEPS;   // 4096 (INPUT=1)
    const int grid = B / BPB;             // 512 blocks
    lstm_fused_kernel<<<grid, BLOCK, 0, stream>>>(x, W_ih, W_hh, b_ih, b_hh,
                                                  W_fc, b_fc, out);
}

// Round 2
// 277.146 us; speedup vs baseline: 1.3665x; 1.3665x over previous
//
#include <hip/hip_runtime.h>

// LSTM: B=4096, T=512, INPUT=1, HIDDEN=32, OUTPUT=1 (fp32)
// One 64-lane wave per block handles 2 batch elements (one per 32-lane half).
// Lane j owns hidden unit j: 4 recurrent weight rows (128 fp32) in VGPRs.
// h is exchanged through a per-half LDS row; barrier-free (intra-wave DS is
// in-order; a compiler memory fence prevents illegal hoisting).

#define HID 32
#define TSTEPS 512
#define BPW 2            // batch elements per wave/block
#define BLOCK 64

__device__ __forceinline__ float rcp_fast(float x) {
    return __builtin_amdgcn_rcpf(x);            // v_rcp_f32, ~1 ulp
}
__device__ __forceinline__ float sigmoid_fast(float x) {
    return rcp_fast(1.0f + __expf(-x));         // mul+exp+add+rcp
}
__device__ __forceinline__ float tanh_fast(float x) {
    return fmaf(2.0f, rcp_fast(1.0f + __expf(-2.0f * x)), -1.0f);
}

__global__ __launch_bounds__(BLOCK)
__attribute__((amdgpu_waves_per_eu(2, 2)))
void lstm_fused_kernel(const float* __restrict__ x,
                       const float* __restrict__ W_ih,
                       const float* __restrict__ W_hh,
                       const float* __restrict__ b_ih,
                       const float* __restrict__ b_hh,
                       const float* __restrict__ W_fc,
                       const float* __restrict__ b_fc,
                       float* __restrict__ out)
{
    __shared__ __align__(16) float x_s[BPW * TSTEPS];   // 4 KiB
    __shared__ __align__(16) float h_s[BPW][HID];       // 256 B

    const int tid = threadIdx.x;
    const int lb  = tid >> 5;        // local batch 0..1 (half-wave)
    const int j   = tid & 31;        // hidden unit
    const int b0  = blockIdx.x * BPW;

    // ---- stage x for this wave's 2 batch rows (coalesced float4) ----
    {
        const float4* xsrc = reinterpret_cast<const float4*>(x + (size_t)b0 * TSTEPS);
        float4* xdst = reinterpret_cast<float4*>(x_s);
        #pragma unroll
        for (int k = 0; k < (BPW * TSTEPS) / (4 * BLOCK); ++k)
            xdst[tid + k * BLOCK] = xsrc[tid + k * BLOCK];
    }

    // ---- per-unit weights into registers: rows j, 32+j, 64+j, 96+j ----
    float w0[HID], w1[HID], w2[HID], w3[HID];
    {
        const float4* r0 = reinterpret_cast<const float4*>(W_hh + (size_t)(0 * HID + j) * HID);
        const float4* r1 = reinterpret_cast<const float4*>(W_hh + (size_t)(1 * HID + j) * HID);
        const float4* r2 = reinterpret_cast<const float4*>(W_hh + (size_t)(2 * HID + j) * HID);
        const float4* r3 = reinterpret_cast<const float4*>(W_hh + (size_t)(3 * HID + j) * HID);
        #pragma unroll
        for (int k = 0; k < HID / 4; ++k) {
            float4 v;
            v = r0[k]; w0[4*k]=v.x; w0[4*k+1]=v.y; w0[4*k+2]=v.z; w0[4*k+3]=v.w;
            v = r1[k]; w1[4*k]=v.x; w1[4*k+1]=v.y; w1[4*k+2]=v.z; w1[4*k+3]=v.w;
            v = r2[k]; w2[4*k]=v.x; w2[4*k+1]=v.y; w2[4*k+2]=v.z; w2[4*k+3]=v.w;
            v = r3[k]; w3[4*k]=v.x; w3[4*k+1]=v.y; w3[4*k+2]=v.z; w3[4*k+3]=v.w;
        }
    }
    const float wih0 = W_ih[j],           wih1 = W_ih[HID + j];
    const float wih2 = W_ih[2*HID + j],   wih3 = W_ih[3*HID + j];
    const float bs0  = b_ih[j]           + b_hh[j];
    const float bs1  = b_ih[HID + j]     + b_hh[HID + j];
    const float bs2  = b_ih[2*HID + j]   + b_hh[2*HID + j];
    const float bs3  = b_ih[3*HID + j]   + b_hh[3*HID + j];

    // ---- init state ----
    h_s[lb][j] = 0.0f;
    float c = 0.0f;
    float hcur = 0.0f;
    __syncthreads();   // single-wave block: trivial; orders staging

    // ---- recurrence: no barriers (intra-wave LDS is in-order) ----
    #pragma unroll 1
    for (int t = 0; t < TSTEPS; ++t) {
        const float xv = x_s[lb * TSTEPS + t];

        float a0 = fmaf(xv, wih0, bs0);
        float a1 = fmaf(xv, wih1, bs1);
        float a2 = fmaf(xv, wih2, bs2);
        float a3 = fmaf(xv, wih3, bs3);

        const float4* hr = reinterpret_cast<const float4*>(&h_s[lb][0]);
        #pragma unroll
        for (int k = 0; k < HID / 4; ++k) {
            float4 hv = hr[k];
            a0 = fmaf(hv.x, w0[4*k  ], a0);
            a1 = fmaf(hv.x, w1[4*k  ], a1);
            a2 = fmaf(hv.x, w2[4*k  ], a2);
            a3 = fmaf(hv.x, w3[4*k  ], a3);
            a0 = fmaf(hv.y, w0[4*k+1], a0);
            a1 = fmaf(hv.y, w1[4*k+1], a1);
            a2 = fmaf(hv.y, w2[4*k+1], a2);
            a3 = fmaf(hv.y, w3[4*k+1], a3);
            a0 = fmaf(hv.z, w0[4*k+2], a0);
            a1 = fmaf(hv.z, w1[4*k+2], a1);
            a2 = fmaf(hv.z, w2[4*k+2], a2);
            a3 = fmaf(hv.z, w3[4*k+2], a3);
            a0 = fmaf(hv.w, w0[4*k+3], a0);
            a1 = fmaf(hv.w, w1[4*k+3], a1);
            a2 = fmaf(hv.w, w2[4*k+3], a2);
            a3 = fmaf(hv.w, w3[4*k+3], a3);
        }

        const float ig = sigmoid_fast(a0);
        const float fg = sigmoid_fast(a1);
        const float gg = tanh_fast(a2);
        const float og = sigmoid_fast(a3);
        c    = fmaf(fg, c, ig * gg);
        hcur = og * tanh_fast(c);

        h_s[lb][j] = hcur;
        // compiler fence: forbid hoisting next iteration's h reads above this
        // write (HW: same-wave DS ops complete in order, no barrier needed)
        asm volatile("" ::: "memory");
    }

    // ---- final FC: out[b] = dot(h_T, W_fc) + b_fc ----
    float p = hcur * W_fc[j];
    #pragma unroll
    for (int off = 16; off >= 1; off >>= 1)
        p += __shfl_xor(p, off);   // xor masks <=16 stay within each half
    if (j == 0)
        out[b0 + lb] = p + b_fc[0];
}

extern "C" void kernel_launch(void* const* d_in, const int* in_sizes, int n_in,
                              void* d_out, int out_size, void* d_ws, size_t ws_size,
                              hipStream_t stream) {
    const float* x    = (const float*)d_in[0];
    const float* W_ih = (const float*)d_in[1];
    const float* W_hh = (const float*)d_in[2];
    const float* b_ih = (const float*)d_in[3];
    const float* b_hh = (const float*)d_in[4];
    const float* W_fc = (const float*)d_in[5];
    const float* b_fc = (const float*)d_in[6];
    float* out = (float*)d_out;

    const int B = in_sizes[0] / TSTEPS;   // 4096 (INPUT=1)
    const int grid = B / BPW;             // 2048 blocks, 1 wave each
    lstm_fused_kernel<<<grid, BLOCK, 0, stream>>>(x, W_ih, W_hh, b_ih, b_hh,
                                                  W_fc, b_fc, out);
}